// Round 1
// baseline (261.754 us; speedup 1.0000x reference)
//
#include <hip/hip_runtime.h>

#define BB 4096
#define TN 512
#define IN 13
#define HN 7
#define NG 28   // 4*H
#define FFD 512
#define CT 32   // timestep chunk staged in LDS
#define GPB 8   // batch elements (32-lane groups) per 256-thread block

__global__ __launch_bounds__(256, 2)
void lstm_fused(const float* __restrict__ x,
                const float* __restrict__ w_ih,
                const float* __restrict__ w_hh,
                const float* __restrict__ b_ih,
                const float* __restrict__ b_hh,
                const float* __restrict__ fc1_w,
                const float* __restrict__ fc1_b,
                const float* __restrict__ fc_w,
                const float* __restrict__ fc_b,
                float* __restrict__ out)
{
    __shared__ float xs[GPB][CT][16];   // rows padded 13->16 for aligned b128 reads

    const int tid  = threadIdx.x;
    const int grp  = tid >> 5;          // batch group within block
    const int lane = tid & 31;          // lane within 32-lane group
    const int b    = blockIdx.x * GPB + grp;
    const int gg   = (lane < NG) ? lane : (NG - 1);   // clamp idle lanes in-bounds

    // per-lane gate weights in registers
    float wih[IN], whh[HN];
#pragma unroll
    for (int i = 0; i < IN; ++i) wih[i] = w_ih[gg * IN + i];
#pragma unroll
    for (int j = 0; j < HN; ++j) whh[j] = w_hh[gg * HN + j];
    const float bias = b_ih[gg] + b_hh[gg];

    // gate order i(0-6), f(7-13), g(14-20 tanh), o(21-27)
    const bool  is_tanh = (lane >= 14 && lane < 21);
    const float L2E  = 1.4426950408889634f;
    const float kmul = is_tanh ? (-2.0f * L2E) : (-L2E);
    const float sc   = is_tanh ?  2.0f : 1.0f;
    const float offc = is_tanh ? -1.0f : 0.0f;

    float hval = 0.0f;   // lane j<7 owns h[j]
    float cval = 0.0f;   // lane j<7 owns c[j]

    for (int t0 = 0; t0 < TN; t0 += CT) {
        __syncthreads();
        // stage x[b0..b0+7, t0..t0+CT, 0..12] into LDS (contiguous per batch)
        for (int idx = tid; idx < GPB * CT * IN; idx += 256) {
            int bb  = idx / (CT * IN);
            int rem = idx - bb * (CT * IN);
            int t   = rem / IN;
            int i   = rem - t * IN;
            xs[bb][t][i] =
                x[((long)(blockIdx.x * GPB + bb) * TN + (t0 + t)) * IN + i];
        }
        __syncthreads();

        for (int tt = 0; tt < CT; ++tt) {
            const float* xr = xs[grp][tt];
            float s = bias;
#pragma unroll
            for (int i = 0; i < IN; ++i) s = fmaf(wih[i], xr[i], s);
#pragma unroll
            for (int j = 0; j < HN; ++j)
                s = fmaf(whh[j], __shfl(hval, j, 32), s);

            // activation: sigmoid = 1/(1+2^(-s*log2e)); tanh = 2*sig(2s)-1
            float e   = __builtin_amdgcn_exp2f(kmul * s);
            float r   = __builtin_amdgcn_rcpf(1.0f + e);
            float val = fmaf(r, sc, offc);

            float iv = val;
            float fv = __shfl(val, lane + 7,  32);
            float gv = __shfl(val, lane + 14, 32);
            float ov = __shfl(val, lane + 21, 32);

            cval = fmaf(fv, cval, iv * gv);
            float e2 = __builtin_amdgcn_exp2f(-2.0f * L2E * cval);
            float th = fmaf(__builtin_amdgcn_rcpf(1.0f + e2), 2.0f, -1.0f);
            hval = ov * th;
        }
    }

    // epilogue: relu -> fc1(512x7) -> relu -> fc(1x512)
    float hr = fmaxf(hval, 0.0f);
    float hb[HN];
#pragma unroll
    for (int j = 0; j < HN; ++j) hb[j] = __shfl(hr, j, 32);

    float acc = 0.0f;
#pragma unroll
    for (int k = 0; k < FFD / 32; ++k) {
        int row = lane + (k << 5);
        float s = fc1_b[row];
#pragma unroll
        for (int j = 0; j < HN; ++j) s = fmaf(fc1_w[row * HN + j], hb[j], s);
        s = fmaxf(s, 0.0f);
        acc = fmaf(fc_w[row], s, acc);
    }
#pragma unroll
    for (int o = 16; o >= 1; o >>= 1) acc += __shfl_xor(acc, o, 32);
    if (lane == 0) out[b] = acc + fc_b[0];
}

extern "C" void kernel_launch(void* const* d_in, const int* in_sizes, int n_in,
                              void* d_out, int out_size, void* d_ws, size_t ws_size,
                              hipStream_t stream) {
    const float* x     = (const float*)d_in[0];
    const float* w_ih  = (const float*)d_in[1];
    const float* w_hh  = (const float*)d_in[2];
    const float* b_ih  = (const float*)d_in[3];
    const float* b_hh  = (const float*)d_in[4];
    const float* fc1_w = (const float*)d_in[5];
    const float* fc1_b = (const float*)d_in[6];
    const float* fc_w  = (const float*)d_in[7];
    const float* fc_b  = (const float*)d_in[8];
    float* out = (float*)d_out;

    dim3 grid(BB / GPB);   // 512 blocks, 8 batch elements each
    dim3 block(256);
    hipLaunchKernelGGL(lstm_fused, grid, block, 0, stream,
                       x, w_ih, w_hh, b_ih, b_hh, fc1_w, fc1_b, fc_w, fc_b, out);
}

// Round 3
// 165.508 us; speedup vs baseline: 1.5815x; 1.5815x over previous
//
#include <hip/hip_runtime.h>

#define BB 4096
#define TN 512
#define IN 13
#define HN 7
#define FFD 512
#define CT 32   // timestep chunk staged in LDS
#define GPB 8   // batch elements (32-lane groups) per 256-thread block

// cross-lane helpers (defined semantics -> no compiler-reordering hazard)
#define SWZ(v, imm) __int_as_float(__builtin_amdgcn_ds_swizzle(__float_as_int(v), (imm)))
#define QB(v, q)    __int_as_float(__builtin_amdgcn_mov_dpp(__float_as_int(v), (q)*0x55, 0xF, 0xF, true))

__global__ __launch_bounds__(256, 2)
void lstm_fused(const float* __restrict__ x,
                const float* __restrict__ w_ih,
                const float* __restrict__ w_hh,
                const float* __restrict__ b_ih,
                const float* __restrict__ b_hh,
                const float* __restrict__ fc1_w,
                const float* __restrict__ fc1_b,
                const float* __restrict__ fc_w,
                const float* __restrict__ fc_b,
                float* __restrict__ out)
{
    __shared__ float xs[GPB][CT][16];   // rows padded 13->16 for aligned b128 reads

    const int tid  = threadIdx.x;
    const int grp  = tid >> 5;          // batch group within block
    const int lane = tid & 31;          // lane within 32-lane group
    const int b    = blockIdx.x * GPB + grp;

    // interleaved gate layout: quad j = hidden unit j, tau = lane&3 (0=i,1=f,2=g,3=o)
    const int tau = lane & 3;
    const int ju  = lane >> 2;                    // unit 0..7 (7 = idle quad)
    const int jj  = (ju < HN) ? ju : (HN - 1);    // clamp idle quad in-bounds
    const int row = tau * HN + jj;                // PyTorch row in 4H

    float wih[IN], whh[HN];
#pragma unroll
    for (int i = 0; i < IN; ++i) wih[i] = w_ih[row * IN + i];
#pragma unroll
    for (int k = 0; k < HN; ++k) whh[k] = w_hh[row * HN + k];
    const float bias = b_ih[row] + b_hh[row];

    const float L2E  = 1.4426950408889634f;
    const bool  is_tanh = (tau == 2);
    const float kmul = is_tanh ? (-2.0f * L2E) : (-L2E);
    const float sc   = is_tanh ?  2.0f : 1.0f;
    const float offc = is_tanh ? -1.0f : 0.0f;

    float h0 = 0.f, h1 = 0.f, h2 = 0.f, h3 = 0.f, h4 = 0.f, h5 = 0.f, h6 = 0.f;
    float cval = 0.0f;   // c_j replicated across quad j

    for (int t0 = 0; t0 < TN; t0 += CT) {
        __syncthreads();
        for (int idx = tid; idx < GPB * CT * IN; idx += 256) {
            int bb  = idx / (CT * IN);
            int rem = idx - bb * (CT * IN);
            int t   = rem / IN;
            int i   = rem - t * IN;
            xs[bb][t][i] =
                x[((long)(blockIdx.x * GPB + bb) * TN + (t0 + t)) * IN + i];
        }
        __syncthreads();

        // ---- phase 1: x-projection for the whole chunk (parallel, ILP) ----
        float xdot[CT];
#pragma unroll
        for (int tt = 0; tt < CT; ++tt) {
            const float* xr = xs[grp][tt];
            const float4 a  = *(const float4*)(xr);
            const float4 b4 = *(const float4*)(xr + 4);
            const float4 c4 = *(const float4*)(xr + 8);
            const float  d0 = xr[12];
            float s0 = fmaf(wih[0], a.x, bias);
            s0 = fmaf(wih[1], a.y, s0);
            s0 = fmaf(wih[2], a.z, s0);
            s0 = fmaf(wih[3], a.w, s0);
            float s1 = wih[4] * b4.x;
            s1 = fmaf(wih[5], b4.y, s1);
            s1 = fmaf(wih[6], b4.z, s1);
            s1 = fmaf(wih[7], b4.w, s1);
            float s2 = wih[8] * c4.x;
            s2 = fmaf(wih[9],  c4.y, s2);
            s2 = fmaf(wih[10], c4.z, s2);
            s2 = fmaf(wih[11], c4.w, s2);
            s2 = fmaf(wih[12], d0,   s2);
            xdot[tt] = (s0 + s1) + s2;
        }

        // ---- phase 2: recurrence (serial; all cross-lane via intrinsics) ----
#pragma unroll
        for (int tt = 0; tt < CT; ++tt) {
            float s0 = fmaf(whh[0], h0, xdot[tt]);
            s0 = fmaf(whh[1], h1, s0);
            s0 = fmaf(whh[2], h2, s0);
            s0 = fmaf(whh[3], h3, s0);
            float s1 = whh[4] * h4;
            s1 = fmaf(whh[5], h5, s1);
            s1 = fmaf(whh[6], h6, s1);
            const float s = s0 + s1;

            // per-tau activation: sigmoid or tanh (tanh = 2*sig(2s)-1)
            float e   = __builtin_amdgcn_exp2f(kmul * s);
            float val = fmaf(__builtin_amdgcn_rcpf(1.0f + e), sc, offc);

            // quad broadcast of the 4 gate values (pure VALU)
            float iv = QB(val, 0);
            float fv = QB(val, 1);
            float gv = QB(val, 2);
            float ov = QB(val, 3);

            cval = fmaf(fv, cval, iv * gv);
            float e2 = __builtin_amdgcn_exp2f(-2.0f * L2E * cval);
            float th = fmaf(__builtin_amdgcn_rcpf(1.0f + e2), 2.0f, -1.0f);
            float hq = ov * th;            // h_j on all lanes of quad j

            // broadcast h_j (lane 4j) to all 32 lanes of the group
            h0 = SWZ(hq, (0 << 5));
            h1 = SWZ(hq, (4 << 5));
            h2 = SWZ(hq, (8 << 5));
            h3 = SWZ(hq, (12 << 5));
            h4 = SWZ(hq, (16 << 5));
            h5 = SWZ(hq, (20 << 5));
            h6 = SWZ(hq, (24 << 5));
        }
    }

    // epilogue: relu -> fc1(512x7) -> relu -> fc(1x512); h replicated in regs
    float hb[HN] = { fmaxf(h0,0.f), fmaxf(h1,0.f), fmaxf(h2,0.f), fmaxf(h3,0.f),
                     fmaxf(h4,0.f), fmaxf(h5,0.f), fmaxf(h6,0.f) };

    float acc = 0.0f;
#pragma unroll
    for (int k = 0; k < FFD / 32; ++k) {
        int r = lane + (k << 5);
        float s = fc1_b[r];
#pragma unroll
        for (int j = 0; j < HN; ++j) s = fmaf(fc1_w[r * HN + j], hb[j], s);
        s = fmaxf(s, 0.0f);
        acc = fmaf(fc_w[r], s, acc);
    }
#pragma unroll
    for (int o = 16; o >= 1; o >>= 1) acc += __shfl_xor(acc, o, 32);
    if (lane == 0) out[b] = acc + fc_b[0];
}

extern "C" void kernel_launch(void* const* d_in, const int* in_sizes, int n_in,
                              void* d_out, int out_size, void* d_ws, size_t ws_size,
                              hipStream_t stream) {
    const float* x     = (const float*)d_in[0];
    const float* w_ih  = (const float*)d_in[1];
    const float* w_hh  = (const float*)d_in[2];
    const float* b_ih  = (const float*)d_in[3];
    const float* b_hh  = (const float*)d_in[4];
    const float* fc1_w = (const float*)d_in[5];
    const float* fc1_b = (const float*)d_in[6];
    const float* fc_w  = (const float*)d_in[7];
    const float* fc_b  = (const float*)d_in[8];
    float* out = (float*)d_out;

    dim3 grid(BB / GPB);   // 512 blocks, 8 batch elements each
    dim3 block(256);
    hipLaunchKernelGGL(lstm_fused, grid, block, 0, stream,
                       x, w_ih, w_hh, b_ih, b_hh, fc1_w, fc1_b, fc_w, fc_b, out);
}

// Round 4
// 107.857 us; speedup vs baseline: 2.4269x; 1.5345x over previous
//
#include <hip/hip_runtime.h>

#define BB 4096
#define TN 512
#define IN 13
#define HN 7
#define FFD 512
#define CT 32            // timesteps staged per chunk
#define SC 8             // sub-chunk: xdot register block
#define NCK (TN / CT)    // 16 chunks
#define GPB 2            // chains per 64-thread block (one per 32-lane group)

// cross-lane helpers (defined semantics -> no compiler-reordering hazard)
#define SWZ(v, imm) __int_as_float(__builtin_amdgcn_ds_swizzle(__float_as_int(v), (imm)))
#define QB(v, q)    __int_as_float(__builtin_amdgcn_mov_dpp(__float_as_int(v), (q)*0x55, 0xF, 0xF, true))

__global__ __launch_bounds__(64, 2)
void lstm_fused(const float* __restrict__ x,
                const float* __restrict__ w_ih,
                const float* __restrict__ w_hh,
                const float* __restrict__ b_ih,
                const float* __restrict__ b_hh,
                const float* __restrict__ fc1_w,
                const float* __restrict__ fc1_b,
                const float* __restrict__ fc_w,
                const float* __restrict__ fc_b,
                float* __restrict__ out)
{
    __shared__ float xs[2][GPB][CT][16];   // double-buffered, rows padded to 16

    const int tid  = threadIdx.x;
    const int grp  = tid >> 5;          // chain within block
    const int lane = tid & 31;
    const int b    = blockIdx.x * GPB + grp;

    // gate layout: quad j = hidden unit j, tau = lane&3 (0=i,1=f,2=g,3=o)
    const int tau = lane & 3;
    const int ju  = lane >> 2;
    const int jj  = (ju < HN) ? ju : (HN - 1);
    const int row = tau * HN + jj;

    float wih[IN], whh[HN];
#pragma unroll
    for (int i = 0; i < IN; ++i) wih[i] = w_ih[row * IN + i];
#pragma unroll
    for (int k = 0; k < HN; ++k) whh[k] = w_hh[row * HN + k];
    const float bias = b_ih[row] + b_hh[row];

    const float L2E  = 1.4426950408889634f;
    const bool  is_tanh = (tau == 2);
    const float kmul = is_tanh ? (-2.0f * L2E) : (-L2E);
    const float sc   = is_tanh ?  2.0f : 1.0f;
    const float offc = is_tanh ? -1.0f : 0.0f;

    float h0 = 0.f, h1 = 0.f, h2 = 0.f, h3 = 0.f, h4 = 0.f, h5 = 0.f, h6 = 0.f;
    float cval = 0.0f;

    // this thread stages timestep row (t = ck*CT + lane) of its chain
    const float* xrow = x + ((long)b * TN + lane) * IN;

    // ---- stage chunk 0 ----
    {
        const float* src = xrow;                 // ck = 0
        float p[13];
#pragma unroll
        for (int i = 0; i < IN; ++i) p[i] = src[i];
        float* dst = &xs[0][grp][lane][0];
        *(float4*)(dst)     = make_float4(p[0], p[1], p[2],  p[3]);
        *(float4*)(dst + 4) = make_float4(p[4], p[5], p[6],  p[7]);
        *(float4*)(dst + 8) = make_float4(p[8], p[9], p[10], p[11]);
        dst[12] = p[12];
    }
    __syncthreads();

    for (int ck = 0; ck < NCK; ++ck) {
        const int cur = ck & 1;

        // prefetch next chunk into registers (issued now, consumed at bottom)
        float p[13];
        const bool havenext = (ck + 1 < NCK);
        if (havenext) {
            const float* src = xrow + (ck + 1) * CT * IN;
#pragma unroll
            for (int i = 0; i < IN; ++i) p[i] = src[i];
        }

        // ---- compute: 4 sub-chunks of 8 steps ----
#pragma unroll
        for (int scb = 0; scb < CT / SC; ++scb) {
            // phase 1: x-projection for 8 steps (parallel, register xdot)
            float xdot[SC];
#pragma unroll
            for (int ss = 0; ss < SC; ++ss) {
                const float* xr = &xs[cur][grp][scb * SC + ss][0];
                const float4 a  = *(const float4*)(xr);
                const float4 b4 = *(const float4*)(xr + 4);
                const float4 c4 = *(const float4*)(xr + 8);
                const float  d0 = xr[12];
                float s0 = fmaf(wih[0], a.x, bias);
                s0 = fmaf(wih[1], a.y, s0);
                s0 = fmaf(wih[2], a.z, s0);
                s0 = fmaf(wih[3], a.w, s0);
                float s1 = wih[4] * b4.x;
                s1 = fmaf(wih[5], b4.y, s1);
                s1 = fmaf(wih[6], b4.z, s1);
                s1 = fmaf(wih[7], b4.w, s1);
                float s2 = wih[8] * c4.x;
                s2 = fmaf(wih[9],  c4.y, s2);
                s2 = fmaf(wih[10], c4.z, s2);
                s2 = fmaf(wih[11], c4.w, s2);
                s2 = fmaf(wih[12], d0,   s2);
                xdot[ss] = (s0 + s1) + s2;
            }

            // phase 2: recurrence (serial; intrinsic-only cross-lane)
#pragma unroll
            for (int ss = 0; ss < SC; ++ss) {
                float s0 = fmaf(whh[0], h0, xdot[ss]);
                s0 = fmaf(whh[1], h1, s0);
                s0 = fmaf(whh[2], h2, s0);
                s0 = fmaf(whh[3], h3, s0);
                float s1 = whh[4] * h4;
                s1 = fmaf(whh[5], h5, s1);
                s1 = fmaf(whh[6], h6, s1);
                const float s = s0 + s1;

                float e   = __builtin_amdgcn_exp2f(kmul * s);
                float val = fmaf(__builtin_amdgcn_rcpf(1.0f + e), sc, offc);

                float iv = QB(val, 0);
                float fv = QB(val, 1);
                float gv = QB(val, 2);
                float ov = QB(val, 3);

                cval = fmaf(fv, cval, iv * gv);
                float e2 = __builtin_amdgcn_exp2f(-2.0f * L2E * cval);
                float th = fmaf(__builtin_amdgcn_rcpf(1.0f + e2), 2.0f, -1.0f);
                float hq = ov * th;

                h0 = SWZ(hq, (0  << 5));
                h1 = SWZ(hq, (4  << 5));
                h2 = SWZ(hq, (8  << 5));
                h3 = SWZ(hq, (12 << 5));
                h4 = SWZ(hq, (16 << 5));
                h5 = SWZ(hq, (20 << 5));
                h6 = SWZ(hq, (24 << 5));
            }
        }

        // write prefetched rows into the other buffer (vmcnt wait lands here,
        // ~32 steps after issue -> fully hidden)
        if (havenext) {
            float* dst = &xs[cur ^ 1][grp][lane][0];
            *(float4*)(dst)     = make_float4(p[0], p[1], p[2],  p[3]);
            *(float4*)(dst + 4) = make_float4(p[4], p[5], p[6],  p[7]);
            *(float4*)(dst + 8) = make_float4(p[8], p[9], p[10], p[11]);
            dst[12] = p[12];
        }
        __syncthreads();
    }

    // epilogue: relu -> fc1(512x7) -> relu -> fc(1x512); h replicated in regs
    float hb[HN] = { fmaxf(h0,0.f), fmaxf(h1,0.f), fmaxf(h2,0.f), fmaxf(h3,0.f),
                     fmaxf(h4,0.f), fmaxf(h5,0.f), fmaxf(h6,0.f) };

    float acc = 0.0f;
#pragma unroll
    for (int k = 0; k < FFD / 32; ++k) {
        int r = lane + (k << 5);
        float s = fc1_b[r];
#pragma unroll
        for (int j = 0; j < HN; ++j) s = fmaf(fc1_w[r * HN + j], hb[j], s);
        s = fmaxf(s, 0.0f);
        acc = fmaf(fc_w[r], s, acc);
    }
#pragma unroll
    for (int o = 16; o >= 1; o >>= 1) acc += __shfl_xor(acc, o, 32);
    if (lane == 0) out[b] = acc + fc_b[0];
}

extern "C" void kernel_launch(void* const* d_in, const int* in_sizes, int n_in,
                              void* d_out, int out_size, void* d_ws, size_t ws_size,
                              hipStream_t stream) {
    const float* x     = (const float*)d_in[0];
    const float* w_ih  = (const float*)d_in[1];
    const float* w_hh  = (const float*)d_in[2];
    const float* b_ih  = (const float*)d_in[3];
    const float* b_hh  = (const float*)d_in[4];
    const float* fc1_w = (const float*)d_in[5];
    const float* fc1_b = (const float*)d_in[6];
    const float* fc_w  = (const float*)d_in[7];
    const float* fc_b  = (const float*)d_in[8];
    float* out = (float*)d_out;

    dim3 grid(BB / GPB);   // 2048 one-wave blocks
    dim3 block(64);
    hipLaunchKernelGGL(lstm_fused, grid, block, 0, stream,
                       x, w_ih, w_hh, b_ih, b_hh, fc1_w, fc1_b, fc_w, fc_b, out);
}

// Round 5
// 96.903 us; speedup vs baseline: 2.7012x; 1.1130x over previous
//
#include <hip/hip_runtime.h>

#define BB 4096
#define TN 512
#define IN 13
#define HN 7
#define FFD 512
#define CT 32            // timesteps per chunk
#define NCK (TN / CT)    // 16 chunks
#define GPB 2            // chains per block (one per 32-lane group)

// cross-lane helpers (defined semantics -> no compiler-reordering hazard)
#define SWZ(v, imm) __int_as_float(__builtin_amdgcn_ds_swizzle(__float_as_int(v), (imm)))
#define QB(v, q)    __int_as_float(__builtin_amdgcn_mov_dpp(__float_as_int(v), (q)*0x55, 0xF, 0xF, true))

__global__ __launch_bounds__(128, 4)
void lstm_fused(const float* __restrict__ x,
                const float* __restrict__ w_ih,
                const float* __restrict__ w_hh,
                const float* __restrict__ b_ih,
                const float* __restrict__ b_hh,
                const float* __restrict__ fc1_w,
                const float* __restrict__ fc1_b,
                const float* __restrict__ fc_w,
                const float* __restrict__ fc_b,
                float* __restrict__ out)
{
    __shared__ float xd[2][CT][64];     // gate pre-activation (x-part + bias), dbuf
    __shared__ float xs[GPB][CT][16];   // staged x rows (producer-private)

    const int tid  = threadIdx.x;
    const int wid  = tid >> 6;          // 0 = consumer wave, 1 = producer wave
    const int l64  = tid & 63;
    const int grp  = l64 >> 5;          // chain within block
    const int lane = l64 & 31;
    const int b    = blockIdx.x * GPB + grp;

    // gate layout: quad j = hidden unit j, tau = lane&3 (0=i,1=f,2=g,3=o)
    const int tau = lane & 3;
    const int ju  = lane >> 2;
    const int jj  = (ju < HN) ? ju : (HN - 1);
    const int row = tau * HN + jj;

    const float L2E = 1.4426950408889634f;

    // ---------------- producer state ----------------
    float wih[IN];
    float bias = 0.0f;
    if (wid == 1) {
#pragma unroll
        for (int i = 0; i < IN; ++i) wih[i] = w_ih[row * IN + i];
        bias = b_ih[row] + b_hh[row];
    }

    // produce chunk ck: stage x rows, project, write xd[ck&1]
    auto produce = [&](int ck) {
        const float* src = x + ((long)b * TN + ck * CT + lane) * IN;
        float p[IN];
#pragma unroll
        for (int i = 0; i < IN; ++i) p[i] = src[i];
        float* dst = &xs[grp][lane][0];
        *(float4*)(dst)     = make_float4(p[0], p[1], p[2],  p[3]);
        *(float4*)(dst + 4) = make_float4(p[4], p[5], p[6],  p[7]);
        *(float4*)(dst + 8) = make_float4(p[8], p[9], p[10], p[11]);
        dst[12] = p[12];
        // same-wave LDS RAW: hardware-ordered via lgkmcnt (compiler inserts)
        const int buf = ck & 1;
#pragma unroll
        for (int s = 0; s < CT; ++s) {
            const float* xr = &xs[grp][s][0];
            const float4 a  = *(const float4*)(xr);
            const float4 b4 = *(const float4*)(xr + 4);
            const float4 c4 = *(const float4*)(xr + 8);
            const float  d0 = xr[12];
            float s0 = fmaf(wih[0], a.x, bias);
            s0 = fmaf(wih[1], a.y, s0);
            s0 = fmaf(wih[2], a.z, s0);
            s0 = fmaf(wih[3], a.w, s0);
            float s1 = wih[4] * b4.x;
            s1 = fmaf(wih[5], b4.y, s1);
            s1 = fmaf(wih[6], b4.z, s1);
            s1 = fmaf(wih[7], b4.w, s1);
            float s2 = wih[8] * c4.x;
            s2 = fmaf(wih[9],  c4.y, s2);
            s2 = fmaf(wih[10], c4.z, s2);
            s2 = fmaf(wih[11], c4.w, s2);
            s2 = fmaf(wih[12], d0,   s2);
            xd[buf][s][l64] = (s0 + s1) + s2;
        }
    };

    // ---------------- consumer state ----------------
    float whh[HN];
    if (wid == 0) {
#pragma unroll
        for (int k = 0; k < HN; ++k) whh[k] = w_hh[row * HN + k];
    }
    const bool  is_tanh = (tau == 2);
    const float kmul = is_tanh ? (-2.0f * L2E) : (-L2E);
    const float sc   = is_tanh ?  2.0f : 1.0f;
    const float offc = is_tanh ? -1.0f : 0.0f;

    float h0 = 0.f, h1 = 0.f, h2 = 0.f, h3 = 0.f, h4 = 0.f, h5 = 0.f, h6 = 0.f;
    float cval = 0.0f;

    // ---------------- pipeline ----------------
    if (wid == 1) produce(0);
    __syncthreads();

    for (int ck = 0; ck < NCK; ++ck) {
        if (wid == 1) {
            if (ck + 1 < NCK) produce(ck + 1);
        } else {
            const int buf = ck & 1;
            // prefetch whole chunk of gate pre-activations into registers
            float xr[CT];
#pragma unroll
            for (int s = 0; s < CT; ++s) xr[s] = xd[buf][s][l64];

#pragma unroll
            for (int s = 0; s < CT; ++s) {
                float s0 = fmaf(whh[0], h0, xr[s]);
                s0 = fmaf(whh[1], h1, s0);
                s0 = fmaf(whh[2], h2, s0);
                s0 = fmaf(whh[3], h3, s0);
                float s1 = whh[4] * h4;
                s1 = fmaf(whh[5], h5, s1);
                s1 = fmaf(whh[6], h6, s1);
                const float sg = s0 + s1;

                float e   = __builtin_amdgcn_exp2f(kmul * sg);
                float val = fmaf(__builtin_amdgcn_rcpf(1.0f + e), sc, offc);

                float iv = QB(val, 0);
                float fv = QB(val, 1);
                float gv = QB(val, 2);
                float ov = QB(val, 3);

                cval = fmaf(fv, cval, iv * gv);
                float e2 = __builtin_amdgcn_exp2f(-2.0f * L2E * cval);
                float th = fmaf(__builtin_amdgcn_rcpf(1.0f + e2), 2.0f, -1.0f);
                float hq = ov * th;

                h0 = SWZ(hq, (0  << 5));
                h1 = SWZ(hq, (4  << 5));
                h2 = SWZ(hq, (8  << 5));
                h3 = SWZ(hq, (12 << 5));
                h4 = SWZ(hq, (16 << 5));
                h5 = SWZ(hq, (20 << 5));
                h6 = SWZ(hq, (24 << 5));
            }
        }
        __syncthreads();
    }

    if (wid == 1) return;

    // epilogue (consumer): relu -> fc1(512x7) -> relu -> fc(1x512)
    float hb[HN] = { fmaxf(h0,0.f), fmaxf(h1,0.f), fmaxf(h2,0.f), fmaxf(h3,0.f),
                     fmaxf(h4,0.f), fmaxf(h5,0.f), fmaxf(h6,0.f) };

    float acc = 0.0f;
#pragma unroll
    for (int k = 0; k < FFD / 32; ++k) {
        int r = lane + (k << 5);
        float s = fc1_b[r];
#pragma unroll
        for (int j = 0; j < HN; ++j) s = fmaf(fc1_w[r * HN + j], hb[j], s);
        s = fmaxf(s, 0.0f);
        acc = fmaf(fc_w[r], s, acc);
    }
#pragma unroll
    for (int o = 16; o >= 1; o >>= 1) acc += __shfl_xor(acc, o, 32);
    if (lane == 0) out[b] = acc + fc_b[0];
}

extern "C" void kernel_launch(void* const* d_in, const int* in_sizes, int n_in,
                              void* d_out, int out_size, void* d_ws, size_t ws_size,
                              hipStream_t stream) {
    const float* x     = (const float*)d_in[0];
    const float* w_ih  = (const float*)d_in[1];
    const float* w_hh  = (const float*)d_in[2];
    const float* b_ih  = (const float*)d_in[3];
    const float* b_hh  = (const float*)d_in[4];
    const float* fc1_w = (const float*)d_in[5];
    const float* fc1_b = (const float*)d_in[6];
    const float* fc_w  = (const float*)d_in[7];
    const float* fc_b  = (const float*)d_in[8];
    float* out = (float*)d_out;

    dim3 grid(BB / GPB);   // 2048 blocks x (1 producer + 1 consumer wave)
    dim3 block(128);
    hipLaunchKernelGGL(lstm_fused, grid, block, 0, stream,
                       x, w_ih, w_hh, b_ih, b_hh, fc1_w, fc1_b, fc_w, fc_b, out);
}